// Round 2
// baseline (887.280 us; speedup 1.0000x reference)
//
#include <hip/hip_runtime.h>
#include <hip/hip_bf16.h>

typedef short s16x8 __attribute__((ext_vector_type(8)));
typedef float f32x4 __attribute__((ext_vector_type(4)));
typedef unsigned short u16;
typedef unsigned int u32;

#define TB 64
#define NTHREADS 512

// prep-buffer element offsets (bf16 elements)
#define P_L1 0
#define P_L2 16384
#define P_L3 278528
#define P_L4 540672
#define P_H1 802816
#define P_H2 1327104
#define P_H3 1392640
#define P_H4 1409024
#define P_TOT 1413120

// LDS byte offsets
#define H_OFF 0            // h  [64][512] bf16, row stride 1024B, XOR-swizzled
#define XS_OFF 65536       // xs [64][32]  bf16, row stride 64B
#define ST_OFF 69632       // stage double buffer 2 x 16KB
#define STAGE_HALF 16384
#define Y1_OFF 102400      // y1 [64][256] bf16 (32KB); later aliased: y3 [64][64], y4 [64][32]
#define Y2_OFF 135168      // y2 [64][128] bf16 (16KB)
#define Y3_OFF Y1_OFF
#define Y4_OFF (Y1_OFF + 8192)
#define LDS_BYTES 151552   // 148 KB

__device__ __forceinline__ u16 f2bf(float v) {
  __hip_bfloat16 b = __float2bfloat16(v);
  return __builtin_bit_cast(u16, b);
}
__device__ __forceinline__ float bf2f(u16 u) {
  u32 x = ((u32)u) << 16;
  return __builtin_bit_cast(float, x);
}

// async global->LDS staging: linear copy, wave-uniform LDS base + lane*16
__device__ __forceinline__ void stage_async(const char* g, char* ldsBase, int nbytes, int tid) {
  const int wid = tid >> 6;
  const int lane = tid & 63;
  for (int base = wid * 1024; base < nbytes; base += 8192) {
    __builtin_amdgcn_global_load_lds(
        (const __attribute__((address_space(1))) void*)(g + base + lane * 16),
        (__attribute__((address_space(3))) void*)(ldsBase + base),
        16, 0, 0);
  }
}

// Universal [64 x (NFRAG*... per wave)] chunk GEMM.
// A in LDS (bf16, XOR-swizzled rows), B streamed from prep buffer as [n][32k] units.
// Wave grid: wm in {0,1} -> rows wm*32 + fi*16; bColBase per wave -> chunk cols.
template<int NFRAG, int UPK>
__device__ __forceinline__ void gemm_core(
    char* lds, int aOff, int aRB, int aColBase,
    const char* bGlob, int unitBytes, int kSteps,
    int bColBase, bool active, int tid, int wm,
    f32x4 (&acc)[2][NFRAG])
{
  const int lane = tid & 63;
  const int l15 = lane & 15;
  const int kg = lane >> 4;
#pragma unroll
  for (int fi = 0; fi < 2; ++fi)
#pragma unroll
    for (int fj = 0; fj < NFRAG; ++fj) {
      f32x4 z = {0.f, 0.f, 0.f, 0.f};
      acc[fi][fj] = z;
    }
  const int stageBytes = unitBytes * UPK;
  stage_async(bGlob, lds + ST_OFF, stageBytes, tid);
  for (int ks = 0; ks < kSteps; ++ks) {
    __syncthreads();                       // stage(ks) complete; prev-buf reads done
    const int buf = ks & 1;
    if (ks + 1 < kSteps)
      stage_async(bGlob + (size_t)(ks + 1) * stageBytes,
                  lds + ST_OFF + (buf ^ 1) * STAGE_HALF, stageBytes, tid);
    if (active) {
#pragma unroll
      for (int s = 0; s < UPK; ++s) {
        const int kIdx = (ks * UPK + s) * 32 + kg * 8;
        s16x8 a[2];
#pragma unroll
        for (int fi = 0; fi < 2; ++fi) {
          const int m = wm * 32 + fi * 16 + l15;
          const int sw = ((m & 7) << 4) & (aRB - 1);
          a[fi] = *reinterpret_cast<const s16x8*>(
              lds + aOff + m * aRB + ((((aColBase + kIdx) * 2)) ^ sw));
        }
        const char* ub = lds + ST_OFF + buf * STAGE_HALF + s * unitBytes;
        s16x8 b[NFRAG];
#pragma unroll
        for (int fj = 0; fj < NFRAG; ++fj) {
          const int n = bColBase + fj * 16 + l15;
          b[fj] = *reinterpret_cast<const s16x8*>(ub + n * 64 + kg * 16);
        }
#pragma unroll
        for (int fi = 0; fi < 2; ++fi)
#pragma unroll
          for (int fj = 0; fj < NFRAG; ++fj)
            acc[fi][fj] = __builtin_amdgcn_mfma_f32_16x16x32_bf16(a[fi], b[fj], acc[fi][fj], 0, 0, 0);
      }
    }
  }
  __syncthreads();                         // all reads of stage/A done
}

// direct-store epilogue: bias (+relu) -> bf16 -> swizzled LDS
template<int NFRAG>
__device__ __forceinline__ void epilogue_store(
    char* lds, const f32x4 (&acc)[2][NFRAG],
    int outOff, int outRB, int outColPW,
    const float* biasPtr, int biasBasePW,
    bool relu, int wm, int l15, int rgrp)
{
#pragma unroll
  for (int fj = 0; fj < NFRAG; ++fj) {
    const int gc = outColPW + fj * 16 + l15;
    const float bv = biasPtr[biasBasePW + fj * 16 + l15];
    const int colByte = gc * 2;
#pragma unroll
    for (int fi = 0; fi < 2; ++fi) {
#pragma unroll
      for (int r = 0; r < 4; ++r) {
        const int m = wm * 32 + fi * 16 + rgrp * 4 + r;
        float v = acc[fi][fj][r] + bv;
        if (relu) v = fmaxf(v, 0.f);
        const int sw = ((m & 7) << 4) & (outRB - 1);
        *reinterpret_cast<u16*>(lds + outOff + m * outRB + (colByte ^ sw)) = f2bf(v);
      }
    }
  }
}

// ---------------- weight prep: fp32 -> bf16, transposed into stage units ----------------
__global__ __launch_bounds__(256)
void prep_weights(const float* __restrict__ W1, const float* __restrict__ W2,
                  const float* __restrict__ W3, const float* __restrict__ W4,
                  const float* __restrict__ HW1, const float* __restrict__ HW2,
                  const float* __restrict__ HW3, const float* __restrict__ HW4,
                  u16* __restrict__ wp)
{
  for (int idx = blockIdx.x * blockDim.x + threadIdx.x; idx < P_TOT;
       idx += gridDim.x * blockDim.x) {
    float v;
    if (idx < P_L2) {                                    // L1: 4 units [128n][32k], K pad 30->32
      const int e = idx, u = e >> 12, r = e & 4095, n = r >> 5, k = r & 31;
      const int col = u * 128 + n;
      v = (k < 30) ? W1[k * 512 + col] : 0.f;
    } else if (idx < P_L3) {                             // L2
      const int e = idx - P_L2, u = e >> 12, r = e & 4095, n = r >> 5, k = r & 31;
      const int nc = u >> 4, kc = (u >> 1) & 7, ks = u & 1;
      const int kk = kc * 64 + ks * 32 + k, col = nc * 128 + n;
      v = W2[kk * 512 + col];
    } else if (idx < P_L4) {                             // L3 (pad cols 482..511 with 0)
      const int e = idx - P_L3, u = e >> 12, r = e & 4095, n = r >> 5, k = r & 31;
      const int nc = u >> 4, kc = (u >> 1) & 7, ks = u & 1;
      const int kk = kc * 64 + ks * 32 + k, col = nc * 128 + n;
      v = (col < 482) ? W3[kk * 482 + col] : 0.f;
    } else if (idx < P_H1) {                             // L4
      const int e = idx - P_L4, u = e >> 12, r = e & 4095, n = r >> 5, k = r & 31;
      const int nc = u >> 4, kc = (u >> 1) & 7, ks = u & 1;
      const int kk = kc * 64 + ks * 32 + k, col = nc * 128 + n;
      v = W4[kk * 512 + col];
    } else if (idx < P_H2) {                             // H1: per pair/head
      const int e = idx - P_H1, u = e >> 12, r = e & 4095, n = r >> 5, k = r & 31;
      const int p = u >> 5, nc = (u >> 4) & 1, kc = (u >> 1) & 7, ks = u & 1;
      const int g = 2 * p + nc, kk = kc * 64 + ks * 32 + k;
      v = HW1[((size_t)g * 512 + kk) * 128 + n];
    } else if (idx < P_H3) {                             // H2: [128n] = [head0 64 | head1 64]
      const int e = idx - P_H2, u = e >> 12, r = e & 4095, n = r >> 5, k = r & 31;
      const int p = u >> 2, kc = (u >> 1) & 1, ks = u & 1;
      const int h = n >> 6, g = 2 * p + h, col = n & 63;
      const int kk = kc * 64 + ks * 32 + k;
      v = HW2[((size_t)g * 128 + kk) * 64 + col];
    } else if (idx < P_H4) {                             // H3: [64n] = [h0 32 | h1 32], 4KB units
      const int e = idx - P_H3, u = e >> 11, r = e & 2047, n = r >> 5, k = r & 31;
      const int p = u >> 1, ks = u & 1;
      const int h = n >> 5, g = 2 * p + h, col = n & 31;
      const int kk = ks * 32 + k;
      v = HW3[((size_t)g * 64 + kk) * 32 + col];
    } else {                                             // H4: [32n] = [h0 16 | h1 16], 2KB units
      const int e = idx - P_H4, u = e >> 10, r = e & 1023, n = r >> 5, k = r & 31;
      const int p = u;
      const int h = n >> 4, g = 2 * p + h, col = n & 15;
      v = HW4[((size_t)g * 32 + k) * 16 + col];
    }
    wp[idx] = f2bf(v);
  }
}

// ---------------- fused MLP ----------------
__global__ __launch_bounds__(NTHREADS, 2)
void fused_mlp(const float* __restrict__ x, const u16* __restrict__ wp,
               const float* __restrict__ b1, const float* __restrict__ b2,
               const float* __restrict__ b3, const float* __restrict__ b4,
               const float* __restrict__ Hb1, const float* __restrict__ Hb2,
               const float* __restrict__ Hb3, const float* __restrict__ Hb4,
               const float* __restrict__ hw5, const float* __restrict__ Hb5,
               float* __restrict__ out)
{
  extern __shared__ char lds[];
  const int tid = threadIdx.x;
  const int lane = tid & 63;
  const int l15 = lane & 15;
  const int rgrp = lane >> 4;
  const int wid = tid >> 6;
  const int wm = wid >> 2;          // 0..1  (M-wave)
  const int wn = wid & 3;           // 0..3  (N-wave)
  const int row0 = blockIdx.x * TB;
  const char* wpB = reinterpret_cast<const char*>(wp);

  // ---- phase 0: build x_skip = [x, sin x, cos x, 0, 0] as bf16 in LDS ----
  for (int i = tid; i < TB * 10; i += NTHREADS) {
    const int r = i / 10, c = i % 10;
    const float xv = x[(size_t)(row0 + r) * 10 + c];
    const int sw = (r & 3) << 4;                      // swizzle mask for 64B rows
    char* rowp = lds + XS_OFF + r * 64;
    *reinterpret_cast<u16*>(rowp + ((c * 2) ^ sw)) = f2bf(xv);
    *reinterpret_cast<u16*>(rowp + (((c + 10) * 2) ^ sw)) = f2bf(__sinf(xv));
    *reinterpret_cast<u16*>(rowp + (((c + 20) * 2) ^ sw)) = f2bf(__cosf(xv));
  }
  for (int i = tid; i < TB * 2; i += NTHREADS) {
    const int r = i >> 1, c = 30 + (i & 1);
    const int sw = (r & 3) << 4;
    *reinterpret_cast<u16*>(lds + XS_OFF + r * 64 + ((c * 2) ^ sw)) = 0;
  }
  // visibility handled by first gemm_core's loop-top barrier

  // ---- L1: h = relu(xs @ W1 + b1), K=32(pad), N=512 ----
  for (int nc = 0; nc < 4; ++nc) {
    f32x4 acc[2][2];
    gemm_core<2, 1>(lds, XS_OFF, 64, 0,
                    wpB + (size_t)P_L1 * 2 + (size_t)nc * 8192, 8192, 1,
                    wn * 32, true, tid, wm, acc);
    epilogue_store<2>(lds, acc, H_OFF, 1024, nc * 128 + wn * 32,
                      b1, nc * 128 + wn * 32, true, wm, l15, rgrp);
  }

  // ---- L2 / L3 / L4: h = (relu)(h @ W + b), K=512, N=512, register-parked ----
  for (int layer = 0; layer < 3; ++layer) {
    const float* bias = (layer == 0) ? b2 : (layer == 1) ? b3 : b4;
    const int biasLim = (layer == 1) ? 482 : 512;
    const size_t bbase = (layer == 0) ? (size_t)P_L2 : (layer == 1) ? (size_t)P_L3 : (size_t)P_L4;
    const bool relu = (layer != 2);
    u32 park[4][2][2][2];
#pragma unroll
    for (int nc = 0; nc < 4; ++nc) {
      f32x4 acc[2][2];
      gemm_core<2, 2>(lds, H_OFF, 1024, 0,
                      wpB + bbase * 2 + (size_t)nc * 131072, 8192, 8,
                      wn * 32, true, tid, wm, acc);
#pragma unroll
      for (int fi = 0; fi < 2; ++fi)
#pragma unroll
        for (int fj = 0; fj < 2; ++fj) {
          const int gc = nc * 128 + wn * 32 + fj * 16 + l15;
          const float bv = (gc < biasLim) ? bias[gc] : 0.f;
#pragma unroll
          for (int rp = 0; rp < 2; ++rp) {
            float v0 = acc[fi][fj][rp * 2 + 0] + bv;
            float v1 = acc[fi][fj][rp * 2 + 1] + bv;
            if (relu) { v0 = fmaxf(v0, 0.f); v1 = fmaxf(v1, 0.f); }
            park[nc][fi][fj][rp] = (u32)f2bf(v0) | ((u32)f2bf(v1) << 16);
          }
        }
    }
    // write-back (all compute done via trailing barrier of last chunk)
    const bool isL3 = (layer == 1);
#pragma unroll
    for (int nc2 = 0; nc2 < 4; ++nc2)
#pragma unroll
      for (int fi = 0; fi < 2; ++fi)
#pragma unroll
        for (int fj = 0; fj < 2; ++fj)
#pragma unroll
          for (int rp = 0; rp < 2; ++rp) {
            const u32 pk = park[nc2][fi][fj][rp];
#pragma unroll
            for (int e = 0; e < 2; ++e) {
              const int m = wm * 32 + fi * 16 + rgrp * 4 + rp * 2 + e;
              const int gc = nc2 * 128 + wn * 32 + fj * 16 + l15;
              u16 hv = (u16)(pk >> (e * 16));
              if (isL3 && gc >= 482) {  // concat x_skip, relu applies to it too
                const int c2 = gc - 482;
                const float xv = bf2f(*reinterpret_cast<const u16*>(
                    lds + XS_OFF + m * 64 + ((c2 * 2) ^ ((m & 3) << 4))));
                hv = f2bf(fmaxf(xv, 0.f));
              }
              *reinterpret_cast<u16*>(lds + H_OFF + m * 1024 + ((gc * 2) ^ ((m & 7) << 4))) = hv;
            }
          }
    __syncthreads();
  }

  // ---- heads, processed in pairs p = {2p, 2p+1} ----
  for (int p = 0; p < 4; ++p) {
    // H1: y1[:, nc*128..] = relu(h @ HW1[g] + Hb1[g]), K=512
    for (int nc = 0; nc < 2; ++nc) {
      f32x4 acc[2][2];
      gemm_core<2, 2>(lds, H_OFF, 1024, 0,
                      wpB + (size_t)P_H1 * 2 + (size_t)(p * 32 + nc * 16) * 8192, 8192, 8,
                      wn * 32, true, tid, wm, acc);
      const int g = 2 * p + nc;
      epilogue_store<2>(lds, acc, Y1_OFF, 512, nc * 128 + wn * 32,
                        Hb1 + g * 128, wn * 32, true, wm, l15, rgrp);
    }
    // H2: per-wave head routing (wn>=2 -> head1), K=128
    {
      f32x4 acc[2][2];
      gemm_core<2, 2>(lds, Y1_OFF, 512, (wn >> 1) * 128,
                      wpB + (size_t)P_H2 * 2 + (size_t)p * 4 * 8192, 8192, 2,
                      wn * 32, true, tid, wm, acc);
      const int g = 2 * p + (wn >> 1);
      epilogue_store<2>(lds, acc, Y2_OFF, 256, wn * 32,
                        Hb2 + g * 64, wn * 32 - (wn >> 1) * 64, true, wm, l15, rgrp);
    }
    // H3: K=64, out [64][64] (head = col>>5)
    {
      f32x4 acc[2][1];
      gemm_core<1, 2>(lds, Y2_OFF, 256, (wn >> 1) * 64,
                      wpB + (size_t)P_H3 * 2 + (size_t)p * 8192, 4096, 1,
                      wn * 16, true, tid, wm, acc);
      const int g = 2 * p + (wn >> 1);
      epilogue_store<1>(lds, acc, Y3_OFF, 128, wn * 16,
                        Hb3 + g * 32, wn * 16 - (wn >> 1) * 32, true, wm, l15, rgrp);
    }
    // H4: K=32, out [64][32] (head = col>>4), waves wn<2 active
    {
      f32x4 acc[2][1];
      gemm_core<1, 1>(lds, Y3_OFF, 128, wn * 32,
                      wpB + (size_t)P_H4 * 2 + (size_t)p * 2048, 2048, 1,
                      wn * 16, (wn < 2), tid, wm, acc);
      if (wn < 2) {
        const int g = 2 * p + wn;
        epilogue_store<1>(lds, acc, Y4_OFF, 64, wn * 16,
                          Hb4 + g * 16, 0, true, wm, l15, rgrp);
      }
    }
    __syncthreads();
    // H5: out[b][g] = y4 @ HW5[g] + Hb5[g]  (fp32 dot of 16)
    if (tid < 128) {
      const int r = tid >> 1, hh = tid & 1, g = 2 * p + hh;
      float acc5 = Hb5[g];
      const int sw = (r & 3) << 4;
#pragma unroll
      for (int k = 0; k < 16; ++k) {
        const int c = hh * 16 + k;
        const float yv = bf2f(*reinterpret_cast<const u16*>(
            lds + Y4_OFF + r * 64 + ((c * 2) ^ sw)));
        acc5 += yv * hw5[g * 16 + k];
      }
      out[(size_t)(row0 + r) * 8 + g] = acc5;
    }
  }
}

extern "C" void kernel_launch(void* const* d_in, const int* in_sizes, int n_in,
                              void* d_out, int out_size, void* d_ws, size_t ws_size,
                              hipStream_t stream) {
  (void)in_sizes; (void)n_in; (void)out_size; (void)ws_size;
  const float* x   = (const float*)d_in[0];
  const float* W1  = (const float*)d_in[1];
  const float* b1  = (const float*)d_in[2];
  const float* W2  = (const float*)d_in[3];
  const float* b2  = (const float*)d_in[4];
  const float* W3  = (const float*)d_in[5];
  const float* b3  = (const float*)d_in[6];
  const float* W4  = (const float*)d_in[7];
  const float* b4  = (const float*)d_in[8];
  const float* HW1 = (const float*)d_in[9];
  const float* Hb1 = (const float*)d_in[10];
  const float* HW2 = (const float*)d_in[11];
  const float* Hb2 = (const float*)d_in[12];
  const float* HW3 = (const float*)d_in[13];
  const float* Hb3 = (const float*)d_in[14];
  const float* HW4 = (const float*)d_in[15];
  const float* Hb4 = (const float*)d_in[16];
  const float* HW5 = (const float*)d_in[17];
  const float* Hb5 = (const float*)d_in[18];
  float* out = (float*)d_out;
  u16* wp = (u16*)d_ws;

  prep_weights<<<2048, 256, 0, stream>>>(W1, W2, W3, W4, HW1, HW2, HW3, HW4, wp);

  hipFuncSetAttribute((const void*)fused_mlp,
                      hipFuncAttributeMaxDynamicSharedMemorySize, LDS_BYTES);
  fused_mlp<<<131072 / TB, NTHREADS, LDS_BYTES, stream>>>(
      x, wp, b1, b2, b3, b4, Hb1, Hb2, Hb3, Hb4, HW5, Hb5, out);
}

// Round 3
// 790.940 us; speedup vs baseline: 1.1218x; 1.1218x over previous
//
#include <hip/hip_runtime.h>
#include <hip/hip_bf16.h>

typedef short s16x8 __attribute__((ext_vector_type(8)));
typedef float f32x4 __attribute__((ext_vector_type(4)));
typedef unsigned short u16;
typedef unsigned int u32;

#define TB 64
#define NTHREADS 512

// prep-buffer element offsets (bf16 elements)
#define P_L1 0
#define P_L2 16384
#define P_L3 278528
#define P_L4 540672
#define P_H1 802816
#define P_H2 1327104
#define P_H3 1392640
#define P_H4 1409024
#define P_TOT 1413120

// LDS byte offsets
#define H_OFF   0         // h  [64][1024B] bf16, swz (m&7)<<4
#define XS_OFF  65536     // xs [64][128B]  (data cols 0..31), swz (m&7)<<4
#define STG     73728     // stage dbuf: big 2x32KB spans ..139264; small 2xunit
#define SBH     32768     // big stage half
#define Y1_OFF  106496    // y1 [64][512B]  (aliases big-stage buf1 - ordering handled)
#define Y2_OFF  139264    // y2 [64][256B]
#define Y3_OFF  106496    // y3 [64][128B]  (aliases y1, y1 dead by then)
#define Y4_OFF  114688    // y4 [64][64B]
#define LDS_BYTES 155648  // 152 KB

__device__ __forceinline__ u16 f2bf(float v) {
  __hip_bfloat16 b = __float2bfloat16(v);
  return __builtin_bit_cast(u16, b);
}
__device__ __forceinline__ float bf2f(u16 u) {
  u32 x = ((u32)u) << 16;
  return __builtin_bit_cast(float, x);
}

// async global->LDS staging: linear copy, wave-uniform LDS base + lane*16
__device__ __forceinline__ void stage_async(const char* g, char* ldsBase, int nbytes, int tid) {
  const int wid = tid >> 6;
  const int lane = tid & 63;
  for (int base = wid * 1024; base < nbytes; base += 8192) {
    __builtin_amdgcn_global_load_lds(
        (const __attribute__((address_space(1))) void*)(g + base + lane * 16),
        (__attribute__((address_space(3))) void*)(ldsBase + base),
        16, 0, 0);
  }
}

// ---- big GEMM: 8 waves, fm=4 x fn=4 frags (wave-tile 64x64), K-step 32 ----
// B units in prep buffer: [kg=4][n=nCols][16B] (32KB each; SPLITK: [kw=2][kg=4][256n][16B])
template<bool SPLITK>
__device__ __forceinline__ void gemm4(
    char* lds, int aOff, int aRB, const char* bGlob,
    int nCols, int kSteps, int tid, f32x4 (&acc)[4][4])
{
  const int lane = tid & 63;
  const int l15 = lane & 15;
  const int kg = lane >> 4;
  const int wid = tid >> 6;
  const int colW = SPLITK ? (wid & 3) : wid;
  const int kw = SPLITK ? (wid >> 2) : 0;
#pragma unroll
  for (int i = 0; i < 4; ++i)
#pragma unroll
    for (int j = 0; j < 4; ++j) { f32x4 z = {0.f,0.f,0.f,0.f}; acc[i][j] = z; }

  stage_async(bGlob, lds + STG, SBH, tid);
  for (int ks = 0; ks < kSteps; ++ks) {
    __syncthreads();
    const int buf = ks & 1;
    if (ks + 1 < kSteps)
      stage_async(bGlob + (size_t)(ks + 1) * SBH, lds + STG + (buf ^ 1) * SBH, SBH, tid);
    const char* ub = lds + STG + buf * SBH + (SPLITK ? kw * 16384 : 0);
    const int kA = (SPLITK ? ks * 64 + kw * 32 : ks * 32) + kg * 8;
    s16x8 a[4], b[4];
#pragma unroll
    for (int fi = 0; fi < 4; ++fi) {
      const int m = fi * 16 + l15;
      a[fi] = *reinterpret_cast<const s16x8*>(lds + aOff + m * aRB + ((kA * 2) ^ ((m & 7) << 4)));
    }
#pragma unroll
    for (int fj = 0; fj < 4; ++fj) {
      const int n = colW * 64 + fj * 16 + l15;
      b[fj] = *reinterpret_cast<const s16x8*>(ub + (kg * nCols + n) * 16);
    }
#pragma unroll
    for (int fi = 0; fi < 4; ++fi)
#pragma unroll
      for (int fj = 0; fj < 4; ++fj)
        acc[fi][fj] = __builtin_amdgcn_mfma_f32_16x16x32_bf16(a[fi], b[fj], acc[fi][fj], 0, 0, 0);
  }
  __syncthreads();
}

// backbone epilogue: bias (+relu) (+concat relu(xs) for cols>=482) -> bf16 -> h
__device__ __forceinline__ void epi_bb(char* lds, const f32x4 (&acc)[4][4],
    const float* bias, int biasLim, bool relu, bool concatXS, int tid)
{
  const int lane = tid & 63;
  const int l15 = lane & 15, rgrp = lane >> 4;
  const int wid = tid >> 6;
#pragma unroll
  for (int fj = 0; fj < 4; ++fj) {
    const int gc = wid * 64 + fj * 16 + l15;
    const float bv = (gc < biasLim) ? bias[gc] : 0.f;
#pragma unroll
    for (int fi = 0; fi < 4; ++fi) {
#pragma unroll
      for (int r = 0; r < 4; ++r) {
        const int m = fi * 16 + rgrp * 4 + r;
        float v = acc[fi][fj][r] + bv;
        if (relu) v = fmaxf(v, 0.f);
        u16 hv = f2bf(v);
        if (concatXS && gc >= 482) {
          const int c2 = gc - 482;
          const float xv = bf2f(*reinterpret_cast<const u16*>(
              lds + XS_OFF + m * 128 + ((c2 * 2) ^ ((m & 7) << 4))));
          hv = f2bf(fmaxf(xv, 0.f));
        }
        *reinterpret_cast<u16*>(lds + H_OFF + m * 1024 + ((gc * 2) ^ ((m & 7) << 4))) = hv;
      }
    }
  }
}

// ---- small GEMM for heads H2-H4: fm=2, fn=NFRAG; waves wm=wid>>2, wn=wid&3 ----
template<int NFRAG>
__device__ __forceinline__ void gemm2(
    char* lds, int aOff, int aRB, int aColBase,
    const char* bGlob, int nCols, int unitBytes, int kSteps,
    int bColBase, bool active, int tid, f32x4 (&acc)[2][NFRAG])
{
  const int lane = tid & 63;
  const int l15 = lane & 15;
  const int kg = lane >> 4;
  const int wm = (tid >> 6) >> 2;
#pragma unroll
  for (int fi = 0; fi < 2; ++fi)
#pragma unroll
    for (int fj = 0; fj < NFRAG; ++fj) { f32x4 z = {0.f,0.f,0.f,0.f}; acc[fi][fj] = z; }

  stage_async(bGlob, lds + STG, unitBytes, tid);
  for (int ks = 0; ks < kSteps; ++ks) {
    __syncthreads();
    const int buf = ks & 1;
    if (ks + 1 < kSteps)
      stage_async(bGlob + (size_t)(ks + 1) * unitBytes,
                  lds + STG + (buf ^ 1) * unitBytes, unitBytes, tid);
    if (active) {
      const int kA = aColBase + ks * 32 + kg * 8;
      s16x8 a[2];
#pragma unroll
      for (int fi = 0; fi < 2; ++fi) {
        const int m = wm * 32 + fi * 16 + l15;
        a[fi] = *reinterpret_cast<const s16x8*>(lds + aOff + m * aRB + ((kA * 2) ^ ((m & 7) << 4)));
      }
      const char* ub = lds + STG + buf * unitBytes;
      s16x8 b[NFRAG];
#pragma unroll
      for (int fj = 0; fj < NFRAG; ++fj) {
        const int n = bColBase + fj * 16 + l15;
        b[fj] = *reinterpret_cast<const s16x8*>(ub + (kg * nCols + n) * 16);
      }
#pragma unroll
      for (int fi = 0; fi < 2; ++fi)
#pragma unroll
        for (int fj = 0; fj < NFRAG; ++fj)
          acc[fi][fj] = __builtin_amdgcn_mfma_f32_16x16x32_bf16(a[fi], b[fj], acc[fi][fj], 0, 0, 0);
    }
  }
  __syncthreads();
}

// small epilogue: bias (+relu) -> bf16 -> swizzled LDS (swz masked to row size)
template<int NFRAG>
__device__ __forceinline__ void epilogue_store(
    char* lds, const f32x4 (&acc)[2][NFRAG],
    int outOff, int outRB, int outColPW,
    const float* biasPtr, int biasBasePW,
    bool relu, int wm, int l15, int rgrp)
{
#pragma unroll
  for (int fj = 0; fj < NFRAG; ++fj) {
    const int gc = outColPW + fj * 16 + l15;
    const float bv = biasPtr[biasBasePW + fj * 16 + l15];
    const int colByte = gc * 2;
#pragma unroll
    for (int fi = 0; fi < 2; ++fi) {
#pragma unroll
      for (int r = 0; r < 4; ++r) {
        const int m = wm * 32 + fi * 16 + rgrp * 4 + r;
        float v = acc[fi][fj][r] + bv;
        if (relu) v = fmaxf(v, 0.f);
        const int sw = ((m & 7) << 4) & (outRB - 1);
        *reinterpret_cast<u16*>(lds + outOff + m * outRB + (colByte ^ sw)) = f2bf(v);
      }
    }
  }
}

// ---------------- weight prep: fp32 -> bf16 [kg][n][8j] packets ----------------
__global__ __launch_bounds__(256)
void prep_weights(const float* __restrict__ W1, const float* __restrict__ W2,
                  const float* __restrict__ W3, const float* __restrict__ W4,
                  const float* __restrict__ HW1, const float* __restrict__ HW2,
                  const float* __restrict__ HW3, const float* __restrict__ HW4,
                  u16* __restrict__ wp)
{
  for (int idx = blockIdx.x * blockDim.x + threadIdx.x; idx < P_TOT;
       idx += gridDim.x * blockDim.x) {
    float v;
    if (idx < P_L2) {                       // L1: 1 unit [kg4][512n][8], K pad 30->32
      const int e = idx;
      const int kg = e >> 12, n = (e >> 3) & 511, j = e & 7;
      const int k = kg * 8 + j;
      v = (k < 30) ? W1[k * 512 + n] : 0.f;
    } else if (idx < P_L3) {                // L2: 16 units of 16384
      const int e = idx - P_L2;
      const int u = e >> 14, r = e & 16383;
      const int kg = r >> 12, n = (r >> 3) & 511, j = r & 7;
      const int k = u * 32 + kg * 8 + j;
      v = W2[k * 512 + n];
    } else if (idx < P_L4) {                // L3 (cols >= 482 zero)
      const int e = idx - P_L3;
      const int u = e >> 14, r = e & 16383;
      const int kg = r >> 12, n = (r >> 3) & 511, j = r & 7;
      const int k = u * 32 + kg * 8 + j;
      v = (n < 482) ? W3[k * 482 + n] : 0.f;
    } else if (idx < P_H1) {                // L4
      const int e = idx - P_L4;
      const int u = e >> 14, r = e & 16383;
      const int kg = r >> 12, n = (r >> 3) & 511, j = r & 7;
      const int k = u * 32 + kg * 8 + j;
      v = W4[k * 512 + n];
    } else if (idx < P_H2) {                // H1: 4 pairs x 8 units [kw2][kg4][256n][8]
      const int e = idx - P_H1;
      const int p = e >> 17, r = e & 131071;
      const int u = r >> 14, q = r & 16383;
      const int kw = q >> 13, kg = (q >> 11) & 3, n = (q >> 3) & 255, j = q & 7;
      const int k = u * 64 + kw * 32 + kg * 8 + j;
      const int g = 2 * p + (n >> 7), col = n & 127;
      v = HW1[((size_t)g * 512 + k) * 128 + col];
    } else if (idx < P_H3) {                // H2: 4 pairs x 4 units [kg4][128n][8]
      const int e = idx - P_H2;
      const int p = e >> 14, r = e & 16383;
      const int u = r >> 12, q = r & 4095;
      const int kg = q >> 10, n = (q >> 3) & 127, j = q & 7;
      const int k = u * 32 + kg * 8 + j;
      const int g = 2 * p + (n >> 6), col = n & 63;
      v = HW2[((size_t)g * 128 + k) * 64 + col];
    } else if (idx < P_H4) {                // H3: 4 pairs x 2 units [kg4][64n][8]
      const int e = idx - P_H3;
      const int p = e >> 12, r = e & 4095;
      const int u = r >> 11, q = r & 2047;
      const int kg = q >> 9, n = (q >> 3) & 63, j = q & 7;
      const int k = u * 32 + kg * 8 + j;
      const int g = 2 * p + (n >> 5), col = n & 31;
      v = HW3[((size_t)g * 64 + k) * 32 + col];
    } else {                                // H4: 4 pairs x 1 unit [kg4][32n][8]
      const int e = idx - P_H4;
      const int p = e >> 10, q = e & 1023;
      const int kg = q >> 8, n = (q >> 3) & 31, j = q & 7;
      const int k = kg * 8 + j;
      const int g = 2 * p + (n >> 4), col = n & 15;
      v = HW4[((size_t)g * 32 + k) * 16 + col];
    }
    wp[idx] = f2bf(v);
  }
}

// ---------------- fused MLP ----------------
__global__ __launch_bounds__(NTHREADS, 2)
void fused_mlp(const float* __restrict__ x, const u16* __restrict__ wp,
               const float* __restrict__ b1, const float* __restrict__ b2,
               const float* __restrict__ b3, const float* __restrict__ b4,
               const float* __restrict__ Hb1, const float* __restrict__ Hb2,
               const float* __restrict__ Hb3, const float* __restrict__ Hb4,
               const float* __restrict__ hw5, const float* __restrict__ Hb5,
               float* __restrict__ out)
{
  extern __shared__ char lds[];
  const int tid = threadIdx.x;
  const int lane = tid & 63;
  const int l15 = lane & 15;
  const int rgrp = lane >> 4;
  const int wid = tid >> 6;
  const int wm = wid >> 2;          // small-gemm M-wave / split-K K-wave
  const int wn = wid & 3;           // small-gemm N-wave / split-K N-wave
  const int row0 = blockIdx.x * TB;
  const char* wpB = reinterpret_cast<const char*>(wp);

  // ---- phase 0: xs = [x, sin x, cos x, 0, 0] bf16, rows 128B swizzled ----
  for (int i = tid; i < TB * 10; i += NTHREADS) {
    const int r = i / 10, c = i % 10;
    const float xv = x[(size_t)(row0 + r) * 10 + c];
    const int sw = (r & 7) << 4;
    char* rowp = lds + XS_OFF + r * 128;
    *reinterpret_cast<u16*>(rowp + ((c * 2) ^ sw)) = f2bf(xv);
    *reinterpret_cast<u16*>(rowp + (((c + 10) * 2) ^ sw)) = f2bf(__sinf(xv));
    *reinterpret_cast<u16*>(rowp + (((c + 20) * 2) ^ sw)) = f2bf(__cosf(xv));
  }
  for (int i = tid; i < TB * 2; i += NTHREADS) {
    const int r = i >> 1, c = 30 + (i & 1);
    *reinterpret_cast<u16*>(lds + XS_OFF + r * 128 + ((c * 2) ^ ((r & 7) << 4))) = 0;
  }
  // visibility via first gemm4's loop-top barrier

  // ---- L1: h = relu(xs @ W1 + b1) ----
  {
    f32x4 acc[4][4];
    gemm4<false>(lds, XS_OFF, 128, wpB + (size_t)P_L1 * 2, 512, 1, tid, acc);
    epi_bb(lds, acc, b1, 512, true, false, tid);
  }
  // ---- L2: relu, L3: relu+concat, L4: no relu ----
  {
    f32x4 acc[4][4];
    gemm4<false>(lds, H_OFF, 1024, wpB + (size_t)P_L2 * 2, 512, 16, tid, acc);
    epi_bb(lds, acc, b2, 512, true, false, tid);
  }
  {
    f32x4 acc[4][4];
    gemm4<false>(lds, H_OFF, 1024, wpB + (size_t)P_L3 * 2, 512, 16, tid, acc);
    epi_bb(lds, acc, b3, 482, true, true, tid);
  }
  {
    f32x4 acc[4][4];
    gemm4<false>(lds, H_OFF, 1024, wpB + (size_t)P_L4 * 2, 512, 16, tid, acc);
    epi_bb(lds, acc, b4, 512, false, false, tid);
  }

  // ---- heads, pairs p = {2p, 2p+1} ----
  for (int p = 0; p < 4; ++p) {
    // H1: split-K 2-way, chunk 64x256 (two heads' 128 cols), K=512
    {
      f32x4 acc[4][4];
      gemm4<true>(lds, H_OFF, 1024, wpB + (size_t)P_H1 * 2 + (size_t)p * 262144,
                  256, 8, tid, acc);
      if (wm == 1) {                       // upper K-wave: write partials (f32)
        char* base = lds + STG + wn * 16384;
#pragma unroll
        for (int fi = 0; fi < 4; ++fi)
#pragma unroll
          for (int fj = 0; fj < 4; ++fj)
#pragma unroll
            for (int r = 0; r < 4; ++r) {
              const int m = fi * 16 + rgrp * 4 + r;
              *reinterpret_cast<float*>(base + (m * 64 + fj * 16 + l15) * 4) = acc[fi][fj][r];
            }
      }
      __syncthreads();
      if (wm == 0) {                       // lower K-wave: accumulate partner
        const char* base = lds + STG + wn * 16384;
#pragma unroll
        for (int fi = 0; fi < 4; ++fi)
#pragma unroll
          for (int fj = 0; fj < 4; ++fj)
#pragma unroll
            for (int r = 0; r < 4; ++r) {
              const int m = fi * 16 + rgrp * 4 + r;
              acc[fi][fj][r] += *reinterpret_cast<const float*>(base + (m * 64 + fj * 16 + l15) * 4);
            }
      }
      __syncthreads();                     // partials consumed before y1 overwrites STG-alias
      if (wm == 0) {                       // epilogue -> y1 [64][512B]
#pragma unroll
        for (int fj = 0; fj < 4; ++fj) {
          const int gc = wn * 64 + fj * 16 + l15;
          const float bv = Hb1[(2 * p + (gc >> 7)) * 128 + (gc & 127)];
#pragma unroll
          for (int fi = 0; fi < 4; ++fi)
#pragma unroll
            for (int r = 0; r < 4; ++r) {
              const int m = fi * 16 + rgrp * 4 + r;
              const float v = fmaxf(acc[fi][fj][r] + bv, 0.f);
              *reinterpret_cast<u16*>(lds + Y1_OFF + m * 512 + ((gc * 2) ^ ((m & 7) << 4))) = f2bf(v);
            }
        }
      }
    }
    // H2: K=128, chunk cols 128 = [h0 64|h1 64]
    {
      f32x4 acc2[2][2];
      gemm2<2>(lds, Y1_OFF, 512, (wn >> 1) * 128,
               wpB + (size_t)P_H2 * 2 + (size_t)p * 32768, 128, 8192, 4,
               wn * 32, true, tid, acc2);
      const int g = 2 * p + (wn >> 1);
      epilogue_store<2>(lds, acc2, Y2_OFF, 256, wn * 32,
                        Hb2 + g * 64, wn * 32 - (wn >> 1) * 64, true, wm, l15, rgrp);
    }
    // H3: K=64, chunk cols 64 = [h0 32|h1 32]
    {
      f32x4 acc2[2][1];
      gemm2<1>(lds, Y2_OFF, 256, (wn >> 1) * 64,
               wpB + (size_t)P_H3 * 2 + (size_t)p * 8192, 64, 4096, 2,
               wn * 16, true, tid, acc2);
      const int g = 2 * p + (wn >> 1);
      epilogue_store<1>(lds, acc2, Y3_OFF, 128, wn * 16,
                        Hb3 + g * 32, wn * 16 - (wn >> 1) * 32, true, wm, l15, rgrp);
    }
    // H4: K=32, chunk cols 32 = [h0 16|h1 16], waves wn<2
    {
      f32x4 acc2[2][1];
      gemm2<1>(lds, Y3_OFF, 128, wn * 32,
               wpB + (size_t)P_H4 * 2 + (size_t)p * 2048, 32, 2048, 1,
               wn * 16, (wn < 2), tid, acc2);
      if (wn < 2) {
        const int g = 2 * p + wn;
        epilogue_store<1>(lds, acc2, Y4_OFF, 64, wn * 16,
                          Hb4 + g * 16, 0, true, wm, l15, rgrp);
      }
    }
    __syncthreads();
    // H5: out[b][g] = y4 @ HW5[g] + Hb5[g] (fp32 dot of 16)
    if (tid < 128) {
      const int r = tid >> 1, hh = tid & 1, g = 2 * p + hh;
      float acc5 = Hb5[g];
      const int sw = (r & 3) << 4;
#pragma unroll
      for (int k = 0; k < 16; ++k) {
        const int c = hh * 16 + k;
        const float yv = bf2f(*reinterpret_cast<const u16*>(
            lds + Y4_OFF + r * 64 + ((c * 2) ^ sw)));
        acc5 += yv * hw5[g * 16 + k];
      }
      out[(size_t)(row0 + r) * 8 + g] = acc5;
    }
    // next pair's H1 loop-top barrier orders y4 reads vs big-stage(1) overwrite
  }
}

extern "C" void kernel_launch(void* const* d_in, const int* in_sizes, int n_in,
                              void* d_out, int out_size, void* d_ws, size_t ws_size,
                              hipStream_t stream) {
  (void)in_sizes; (void)n_in; (void)out_size; (void)ws_size;
  const float* x   = (const float*)d_in[0];
  const float* W1  = (const float*)d_in[1];
  const float* b1  = (const float*)d_in[2];
  const float* W2  = (const float*)d_in[3];
  const float* b2  = (const float*)d_in[4];
  const float* W3  = (const float*)d_in[5];
  const float* b3  = (const float*)d_in[6];
  const float* W4  = (const float*)d_in[7];
  const float* b4  = (const float*)d_in[8];
  const float* HW1 = (const float*)d_in[9];
  const float* Hb1 = (const float*)d_in[10];
  const float* HW2 = (const float*)d_in[11];
  const float* Hb2 = (const float*)d_in[12];
  const float* HW3 = (const float*)d_in[13];
  const float* Hb3 = (const float*)d_in[14];
  const float* HW4 = (const float*)d_in[15];
  const float* Hb4 = (const float*)d_in[16];
  const float* HW5 = (const float*)d_in[17];
  const float* Hb5 = (const float*)d_in[18];
  float* out = (float*)d_out;
  u16* wp = (u16*)d_ws;

  prep_weights<<<2048, 256, 0, stream>>>(W1, W2, W3, W4, HW1, HW2, HW3, HW4, wp);

  hipFuncSetAttribute((const void*)fused_mlp,
                      hipFuncAttributeMaxDynamicSharedMemorySize, LDS_BYTES);
  fused_mlp<<<131072 / TB, NTHREADS, LDS_BYTES, stream>>>(
      x, wp, b1, b2, b3, b4, Hb1, Hb2, Hb3, Hb4, HW5, Hb5, out);
}

// Round 5
// 455.387 us; speedup vs baseline: 1.9484x; 1.7369x over previous
//
#include <hip/hip_runtime.h>
#include <hip/hip_bf16.h>

typedef short s16x8 __attribute__((ext_vector_type(8)));
typedef float f32x4 __attribute__((ext_vector_type(4)));
typedef unsigned short u16;
typedef unsigned int u32;

#define TB 64
#define NTHREADS 512

// prep-buffer element offsets (bf16 elements)
#define P_L1 0
#define P_L2 16384
#define P_L3 278528
#define P_L4 540672
#define P_H1 802816
#define P_H2 1327104
#define P_H3 1392640
#define P_H4 1409024
#define P_TOT 1413120

// LDS byte offsets (no staging buffers anymore; B streams global->regs)
#define H_OFF   0         // h  [64][1024B] bf16, swz (m&7)<<4
#define XS_OFF  65536     // xs [64][128B]  (cols 0..31), swz (m&7)<<4
#define Y1_OFF  73728     // y1 [64][512B]
#define Y2_OFF  106496    // y2 [64][256B]
#define Y3_OFF  122880    // y3 [64][128B]
#define Y4_OFF  131072    // y4 [64][64B]
#define LDS_BYTES 135168  // 132 KB

__device__ __forceinline__ u16 f2bf(float v) {
  __hip_bfloat16 b = __float2bfloat16(v);
  return __builtin_bit_cast(u16, b);
}
__device__ __forceinline__ float bf2f(u16 u) {
  u32 x = ((u32)u) << 16;
  return __builtin_bit_cast(float, x);
}

// load one wave's B fragments for a K32 unit straight into registers
template<int FN>
__device__ __forceinline__ void loadB(s16x8 (&b)[FN], const char* unit,
                                      int nCols, int bColBase, int kg, int l15) {
#pragma unroll
  for (int fj = 0; fj < FN; ++fj) {
    const int n = bColBase + fj * 16 + l15;
    b[fj] = *reinterpret_cast<const s16x8*>(unit + (kg * nCols + n) * 16);
  }
}

// one K32 step: read A frags from LDS, FM*FN MFMAs with B regs
template<int FM, int FN>
__device__ __forceinline__ void mfma_step(
    const char* lds, int aOff, int aRB, int kByte, int mBase, int l15,
    const s16x8 (&b)[FN], f32x4 (&acc)[FM][FN]) {
  s16x8 a[FM];
#pragma unroll
  for (int fi = 0; fi < FM; ++fi) {
    const int m = mBase + fi * 16 + l15;
    a[fi] = *reinterpret_cast<const s16x8*>(
        lds + aOff + m * aRB + (kByte ^ (((m & 7) << 4) & (aRB - 1))));
  }
#pragma unroll
  for (int fi = 0; fi < FM; ++fi)
#pragma unroll
    for (int fj = 0; fj < FN; ++fj)
      acc[fi][fj] = __builtin_amdgcn_mfma_f32_16x16x32_bf16(a[fi], b[fj], acc[fi][fj], 0, 0, 0);
}

// barrier-free K-loop GEMM: A from LDS, B global->regs (named 2-deep dbuf)
template<int FM, int FN, int KSTEPS>
__device__ __forceinline__ void gemm_reg(
    const char* lds, int aOff, int aRB, int aColBase, int mBase,
    const char* bGlob, int unitStride, int nCols, int bColBase,
    int kg, int l15, f32x4 (&acc)[FM][FN]) {
#pragma unroll
  for (int i = 0; i < FM; ++i)
#pragma unroll
    for (int j = 0; j < FN; ++j) { f32x4 z = {0.f,0.f,0.f,0.f}; acc[i][j] = z; }
  s16x8 bA[FN], bB[FN];
  loadB<FN>(bA, bGlob, nCols, bColBase, kg, l15);
#pragma unroll
  for (int ks = 0; ks < KSTEPS; ks += 2) {
    if (ks + 1 < KSTEPS)
      loadB<FN>(bB, bGlob + (size_t)(ks + 1) * unitStride, nCols, bColBase, kg, l15);
    mfma_step<FM, FN>(lds, aOff, aRB, (aColBase + ks * 32 + kg * 8) * 2,
                      mBase, l15, bA, acc);
    if (ks + 1 < KSTEPS) {
      if (ks + 2 < KSTEPS)
        loadB<FN>(bA, bGlob + (size_t)(ks + 2) * unitStride, nCols, bColBase, kg, l15);
      mfma_step<FM, FN>(lds, aOff, aRB, (aColBase + (ks + 1) * 32 + kg * 8) * 2,
                        mBase, l15, bB, acc);
    }
  }
}

// backbone epilogue: bias (+relu) (+concat relu(xs) cols>=482) -> bf16 -> h
__device__ __forceinline__ void epi_bb(char* lds, const f32x4 (&acc)[4][4],
    const float* bias, int biasLim, bool relu, bool concatXS, int tid)
{
  const int lane = tid & 63;
  const int l15 = lane & 15, rgrp = lane >> 4;
  const int wid = tid >> 6;
#pragma unroll
  for (int fj = 0; fj < 4; ++fj) {
    const int gc = wid * 64 + fj * 16 + l15;
    const float bv = (gc < biasLim) ? bias[gc] : 0.f;
#pragma unroll
    for (int fi = 0; fi < 4; ++fi) {
#pragma unroll
      for (int r = 0; r < 4; ++r) {
        const int m = fi * 16 + rgrp * 4 + r;
        float v = acc[fi][fj][r] + bv;
        if (relu) v = fmaxf(v, 0.f);
        u16 hv = f2bf(v);
        if (concatXS && gc >= 482) {
          const int c2 = gc - 482;
          const float xv = bf2f(*reinterpret_cast<const u16*>(
              lds + XS_OFF + m * 128 + ((c2 * 2) ^ ((m & 7) << 4))));
          hv = f2bf(fmaxf(xv, 0.f));
        }
        *reinterpret_cast<u16*>(lds + H_OFF + m * 1024 + ((gc * 2) ^ ((m & 7) << 4))) = hv;
      }
    }
  }
}

// head epilogue: bias (+relu) -> bf16 -> swizzled LDS (swz masked to row size)
template<int NFRAG>
__device__ __forceinline__ void epilogue_store(
    char* lds, const f32x4 (&acc)[2][NFRAG],
    int outOff, int outRB, int outColPW,
    const float* biasPtr, int biasBasePW,
    bool relu, int wm, int l15, int rgrp)
{
#pragma unroll
  for (int fj = 0; fj < NFRAG; ++fj) {
    const int gc = outColPW + fj * 16 + l15;
    const float bv = biasPtr[biasBasePW + fj * 16 + l15];
    const int colByte = gc * 2;
#pragma unroll
    for (int fi = 0; fi < 2; ++fi) {
#pragma unroll
      for (int r = 0; r < 4; ++r) {
        const int m = wm * 32 + fi * 16 + rgrp * 4 + r;
        float v = acc[fi][fj][r] + bv;
        if (relu) v = fmaxf(v, 0.f);
        const int sw = ((m & 7) << 4) & (outRB - 1);
        *reinterpret_cast<u16*>(lds + outOff + m * outRB + (colByte ^ sw)) = f2bf(v);
      }
    }
  }
}

// ---------------- weight prep: fp32 -> bf16 [kg][n][8j] packets ----------------
__global__ __launch_bounds__(256)
void prep_weights(const float* __restrict__ W1, const float* __restrict__ W2,
                  const float* __restrict__ W3, const float* __restrict__ W4,
                  const float* __restrict__ HW1, const float* __restrict__ HW2,
                  const float* __restrict__ HW3, const float* __restrict__ HW4,
                  u16* __restrict__ wp)
{
  for (int idx = blockIdx.x * blockDim.x + threadIdx.x; idx < P_TOT;
       idx += gridDim.x * blockDim.x) {
    float v;
    if (idx < P_L2) {                       // L1: 1 unit [kg4][512n][8], K pad 30->32
      const int e = idx;
      const int kg = e >> 12, n = (e >> 3) & 511, j = e & 7;
      const int k = kg * 8 + j;
      v = (k < 30) ? W1[k * 512 + n] : 0.f;
    } else if (idx < P_L3) {                // L2: 16 units of 16384 elems
      const int e = idx - P_L2;
      const int u = e >> 14, r = e & 16383;
      const int kg = r >> 12, n = (r >> 3) & 511, j = r & 7;
      const int k = u * 32 + kg * 8 + j;
      v = W2[k * 512 + n];
    } else if (idx < P_L4) {                // L3 (cols >= 482 zero)
      const int e = idx - P_L3;
      const int u = e >> 14, r = e & 16383;
      const int kg = r >> 12, n = (r >> 3) & 511, j = r & 7;
      const int k = u * 32 + kg * 8 + j;
      v = (n < 482) ? W3[k * 482 + n] : 0.f;
    } else if (idx < P_H1) {                // L4
      const int e = idx - P_L4;
      const int u = e >> 14, r = e & 16383;
      const int kg = r >> 12, n = (r >> 3) & 511, j = r & 7;
      const int k = u * 32 + kg * 8 + j;
      v = W4[k * 512 + n];
    } else if (idx < P_H2) {                // H1: 4 pairs x 16 units [kg4][256n][8]
      const int e = idx - P_H1;
      const int p = e >> 17, r = e & 131071;
      const int u = r >> 13, q = r & 8191;
      const int kg = q >> 11, n = (q >> 3) & 255, j = q & 7;
      const int k = u * 32 + kg * 8 + j;
      const int g = 2 * p + (n >> 7), col = n & 127;
      v = HW1[((size_t)g * 512 + k) * 128 + col];
    } else if (idx < P_H3) {                // H2: 4 pairs x 4 units [kg4][128n][8]
      const int e = idx - P_H2;
      const int p = e >> 14, r = e & 16383;
      const int u = r >> 12, q = r & 4095;
      const int kg = q >> 10, n = (q >> 3) & 127, j = q & 7;
      const int k = u * 32 + kg * 8 + j;
      const int g = 2 * p + (n >> 6), col = n & 63;
      v = HW2[((size_t)g * 128 + k) * 64 + col];
    } else if (idx < P_H4) {                // H3: 4 pairs x 2 units [kg4][64n][8]
      const int e = idx - P_H3;
      const int p = e >> 12, r = e & 4095;
      const int u = r >> 11, q = r & 2047;
      const int kg = q >> 9, n = (q >> 3) & 63, j = q & 7;
      const int k = u * 32 + kg * 8 + j;
      const int g = 2 * p + (n >> 5), col = n & 31;
      v = HW3[((size_t)g * 64 + k) * 32 + col];
    } else {                                // H4: 4 pairs x 1 unit [kg4][32n][8]
      const int e = idx - P_H4;
      const int p = e >> 10, q = e & 1023;
      const int kg = q >> 8, n = (q >> 3) & 31, j = q & 7;
      const int k = kg * 8 + j;
      const int g = 2 * p + (n >> 4), col = n & 15;
      v = HW4[((size_t)g * 32 + k) * 16 + col];
    }
    wp[idx] = f2bf(v);
  }
}

// ---------------- fused MLP ----------------
__global__ __launch_bounds__(NTHREADS, 2)
void fused_mlp(const float* __restrict__ x, const u16* __restrict__ wp,
               const float* __restrict__ b1, const float* __restrict__ b2,
               const float* __restrict__ b3, const float* __restrict__ b4,
               const float* __restrict__ Hb1, const float* __restrict__ Hb2,
               const float* __restrict__ Hb3, const float* __restrict__ Hb4,
               const float* __restrict__ hw5, const float* __restrict__ Hb5,
               float* __restrict__ out)
{
  extern __shared__ char lds[];
  const int tid = threadIdx.x;
  const int lane = tid & 63;
  const int l15 = lane & 15;
  const int rgrp = lane >> 4;
  const int kg = lane >> 4;        // K-group for fragments
  const int wid = tid >> 6;
  const int wm = wid >> 2;         // head-gemm M-wave
  const int wn = wid & 3;          // head-gemm N-wave
  const int row0 = blockIdx.x * TB;
  const char* wpB = reinterpret_cast<const char*>(wp);

  // ---- phase 0: xs = [x, sin x, cos x, 0, 0] bf16, rows 128B swizzled ----
  for (int i = tid; i < TB * 10; i += NTHREADS) {
    const int r = i / 10, c = i % 10;
    const float xv = x[(size_t)(row0 + r) * 10 + c];
    const int sw = (r & 7) << 4;
    char* rowp = lds + XS_OFF + r * 128;
    *reinterpret_cast<u16*>(rowp + ((c * 2) ^ sw)) = f2bf(xv);
    *reinterpret_cast<u16*>(rowp + (((c + 10) * 2) ^ sw)) = f2bf(__sinf(xv));
    *reinterpret_cast<u16*>(rowp + (((c + 20) * 2) ^ sw)) = f2bf(__cosf(xv));
  }
  for (int i = tid; i < TB * 2; i += NTHREADS) {
    const int r = i >> 1, c = 30 + (i & 1);
    *reinterpret_cast<u16*>(lds + XS_OFF + r * 128 + ((c * 2) ^ ((r & 7) << 4))) = 0;
  }
  __syncthreads();

  // ---- L1: h = relu(xs @ W1 + b1), K=32(pad) ----
  {
    f32x4 acc[4][4];
    gemm_reg<4, 4, 1>(lds, XS_OFF, 128, 0, 0,
                      wpB + (size_t)P_L1 * 2, 8192, 512, wid * 64, kg, l15, acc);
    epi_bb(lds, acc, b1, 512, true, false, tid);   // h-write vs xs-read: disjoint
    __syncthreads();
  }
  // ---- L2: relu, L3: relu+concat, L4: no relu (in-place h, 2 barriers each) ----
  {
    f32x4 acc[4][4];
    gemm_reg<4, 4, 16>(lds, H_OFF, 1024, 0, 0,
                       wpB + (size_t)P_L2 * 2, 32768, 512, wid * 64, kg, l15, acc);
    __syncthreads();                               // all h reads done
    epi_bb(lds, acc, b2, 512, true, false, tid);
    __syncthreads();
  }
  {
    f32x4 acc[4][4];
    gemm_reg<4, 4, 16>(lds, H_OFF, 1024, 0, 0,
                       wpB + (size_t)P_L3 * 2, 32768, 512, wid * 64, kg, l15, acc);
    __syncthreads();
    epi_bb(lds, acc, b3, 482, true, true, tid);
    __syncthreads();
  }
  {
    f32x4 acc[4][4];
    gemm_reg<4, 4, 16>(lds, H_OFF, 1024, 0, 0,
                       wpB + (size_t)P_L4 * 2, 32768, 512, wid * 64, kg, l15, acc);
    __syncthreads();
    epi_bb(lds, acc, b4, 512, false, false, tid);
    __syncthreads();
  }

  // ---- heads, pairs p = {2p, 2p+1} ----
  for (int p = 0; p < 4; ++p) {
    // H1: y1 = relu(h @ HW1[pair] + Hb1), K=512, waves 2M x 4N
    {
      f32x4 acc[2][4];
      gemm_reg<2, 4, 16>(lds, H_OFF, 1024, 0, wm * 32,
                         wpB + (size_t)P_H1 * 2 + (size_t)p * 262144, 16384, 256,
                         wn * 64, kg, l15, acc);
      epilogue_store<4>(lds, acc, Y1_OFF, 512, wn * 64,
                        Hb1 + (2 * p + (wn >> 1)) * 128, wn * 64 - (wn >> 1) * 128,
                        true, wm, l15, rgrp);
      __syncthreads();
    }
    // H2: K=128, per-wave head routing (wn>=2 -> head1)
    {
      f32x4 acc[2][2];
      gemm_reg<2, 2, 4>(lds, Y1_OFF, 512, (wn >> 1) * 128, wm * 32,
                        wpB + (size_t)P_H2 * 2 + (size_t)p * 32768, 8192, 128,
                        wn * 32, kg, l15, acc);
      const int g = 2 * p + (wn >> 1);
      epilogue_store<2>(lds, acc, Y2_OFF, 256, wn * 32,
                        Hb2 + g * 64, wn * 32 - (wn >> 1) * 64, true, wm, l15, rgrp);
      __syncthreads();
    }
    // H3: K=64
    {
      f32x4 acc[2][1];
      gemm_reg<2, 1, 2>(lds, Y2_OFF, 256, (wn >> 1) * 64, wm * 32,
                        wpB + (size_t)P_H3 * 2 + (size_t)p * 8192, 4096, 64,
                        wn * 16, kg, l15, acc);
      const int g = 2 * p + (wn >> 1);
      epilogue_store<1>(lds, acc, Y3_OFF, 128, wn * 16,
                        Hb3 + g * 32, wn * 16 - (wn >> 1) * 32, true, wm, l15, rgrp);
      __syncthreads();
    }
    // H4: K=32, waves wn<2 active
    if (wn < 2) {
      f32x4 acc[2][1];
      gemm_reg<2, 1, 1>(lds, Y3_OFF, 128, wn * 32, wm * 32,
                        wpB + (size_t)P_H4 * 2 + (size_t)p * 2048, 2048, 32,
                        wn * 16, kg, l15, acc);
      const int g = 2 * p + wn;
      epilogue_store<1>(lds, acc, Y4_OFF, 64, wn * 16,
                        Hb4 + g * 16, 0, true, wm, l15, rgrp);
    }
    __syncthreads();
    // H5: out[b][g] = y4 @ HW5[g] + Hb5[g] (fp32 dot of 16)
    if (tid < 128) {
      const int r = tid >> 1, hh = tid & 1, g = 2 * p + hh;
      float acc5 = Hb5[g];
      const int sw = (r & 3) << 4;
#pragma unroll
      for (int k = 0; k < 16; ++k) {
        const int c = hh * 16 + k;
        const float yv = bf2f(*reinterpret_cast<const u16*>(
            lds + Y4_OFF + r * 64 + ((c * 2) ^ sw)));
        acc5 += yv * hw5[g * 16 + k];
      }
      out[(size_t)(row0 + r) * 8 + g] = acc5;
    }
    // next pair's first write (H1-epi into y1) is ordered behind this pair's
    // H2 barrier; y4 readers (H5) protected by barriers inside next pair.
  }
}

extern "C" void kernel_launch(void* const* d_in, const int* in_sizes, int n_in,
                              void* d_out, int out_size, void* d_ws, size_t ws_size,
                              hipStream_t stream) {
  (void)in_sizes; (void)n_in; (void)out_size; (void)ws_size;
  const float* x   = (const float*)d_in[0];
  const float* W1  = (const float*)d_in[1];
  const float* b1  = (const float*)d_in[2];
  const float* W2  = (const float*)d_in[3];
  const float* b2  = (const float*)d_in[4];
  const float* W3  = (const float*)d_in[5];
  const float* b3  = (const float*)d_in[6];
  const float* W4  = (const float*)d_in[7];
  const float* b4  = (const float*)d_in[8];
  const float* HW1 = (const float*)d_in[9];
  const float* Hb1 = (const float*)d_in[10];
  const float* HW2 = (const float*)d_in[11];
  const float* Hb2 = (const float*)d_in[12];
  const float* HW3 = (const float*)d_in[13];
  const float* Hb3 = (const float*)d_in[14];
  const float* HW4 = (const float*)d_in[15];
  const float* Hb4 = (const float*)d_in[16];
  const float* HW5 = (const float*)d_in[17];
  const float* Hb5 = (const float*)d_in[18];
  float* out = (float*)d_out;
  u16* wp = (u16*)d_ws;

  prep_weights<<<2048, 256, 0, stream>>>(W1, W2, W3, W4, HW1, HW2, HW3, HW4, wp);

  hipFuncSetAttribute((const void*)fused_mlp,
                      hipFuncAttributeMaxDynamicSharedMemorySize, LDS_BYTES);
  fused_mlp<<<131072 / TB, NTHREADS, LDS_BYTES, stream>>>(
      x, wp, b1, b2, b3, b4, Hb1, Hb2, Hb3, Hb4, HW5, Hb5, out);
}